// Round 4
// baseline (1457.151 us; speedup 1.0000x reference)
//
#include <hip/hip_runtime.h>
#include <cstdint>
#include <cfloat>

// ---------------------------------------------------------------------------
// SimpleVQVAEEncoder, round 6: R3 base (689 µs) + ONE change:
// register-prefetch + double-buffered LDS, single barrier per K-step.
//   old: sync -> stage(load+ds_write) -> sync -> FMA   (load latency exposed)
//   new: issue loads(t+1) -> FMA(t) -> ds_write(t+1)^buf -> sync
// Staging math is R3's verbatim (wave-uniform k-decomp on SALU, hoisted
// pixel decomp, exec-masked load). WAR-safe: buffer written in iter t was
// last read in iter t-1, before that iter's barrier.
// ---------------------------------------------------------------------------

constexpr int B_    = 128;
constexpr int HW3   = 169;
constexpr int NPIXT = B_ * HW3;        // 21632
constexpr int NEMB  = 512;
constexpr int EMB   = 64;

// transpose weights [OC][K] -> [K][OC] (tiny prepass)
__global__ __launch_bounds__(256) void wtrans_kernel(
    const float* __restrict__ w, float* __restrict__ wt, int OC, int K)
{
    int idx = blockIdx.x * 256 + threadIdx.x;
    if (idx >= OC * K) return;
    int oc = idx / K, k = idx - oc * K;
    wt[(size_t)k * OC + oc] = w[idx];
}

template<int IC, int OC, int KH, int KW, int IH, int IW, int OH, int OW,
         int STRIDE, int PAD, bool RELU, bool TRANSOUT, int OCSPLIT>
__global__ __launch_bounds__(512) void conv_sgemm(
    const float* __restrict__ in, const float* __restrict__ wt,   // wt: [K][OC]
    const float* __restrict__ bias, float* __restrict__ out)
{
    constexpr int K   = IC * KH * KW;
    constexpr int KHW = KH * KW;
    constexpr int BK  = 32;
    constexpr int NIT = K / BK;            // 6 / 72 / 64 — all even
    constexpr int NR  = BK / 8;            // rows staged per wave (4)
    constexpr int NOC = OC / OCSPLIT / 8;  // accs per thread
    constexpr int HWo = OH * OW;

    __shared__ float As[2][BK][64];    // 16 KB; b32 reads: 2-way = free

    const int tid  = threadIdx.x;
    const int lane = tid & 63;
    const int wv   = __builtin_amdgcn_readfirstlane(tid >> 6);  // force uniform
    const int osp  = blockIdx.x % OCSPLIT;
    const int oc0  = osp * (OC / OCSPLIT) + wv * NOC;
    const int pixbase = (blockIdx.x / OCSPLIT) * 64;
    const int krow = wv * NR;              // wave-uniform LDS row base

    // ---- hoisted pixel decomposition (lane-dependent only, once) ----
    const int pix = pixbase + lane;
    const int n   = pix / HWo;
    const int hw  = pix - n * HWo;
    const int oy  = hw / OW;
    const int ox  = hw - oy * OW;
    const int iyb = oy * STRIDE - PAD;
    const int ixb = ox * STRIDE - PAD;
    const float* inb = in + (size_t)n * (IC * IH * IW);

    float acc[NOC];
#pragma unroll
    for (int j = 0; j < NOC; j++) acc[j] = 0.f;

    float rg[NR];
    // R3's staging math, verbatim (k wave-uniform -> SALU decomposition)
    auto stage_load = [&](int k0) {
#pragma unroll
        for (int i = 0; i < NR; i++) {
            int k  = k0 + krow + i;              // uniform
            int ic = k / KHW;                    // uniform -> SALU
            int r  = k - ic * KHW;
            int ky = r / KW;
            int kx = r - ky * KW;
            int iy = iyb + ky;                   // per-lane: 1 add
            int ix = ixb + kx;                   // 1 add
            int off = (ic * IH + iy) * IW + ix;  // mad (ic*IH uniform)
            float v = 0.f;
            if ((unsigned)iy < (unsigned)IH && (unsigned)ix < (unsigned)IW)
                v = inb[off];                    // exec-masked load
            rg[i] = v;
        }
    };

    // prologue: tile 0 into buffer 0
    stage_load(0);
#pragma unroll
    for (int i = 0; i < NR; i++) As[0][krow + i][lane] = rg[i];
    __syncthreads();

#pragma unroll 2
    for (int t = 0; t < NIT; t++) {
        if (t + 1 < NIT) stage_load((t + 1) * BK);       // hide under FMAs
        const float* bp = wt + (size_t)(t * BK) * OC + oc0;  // wave-uniform
        const float* as = &As[t & 1][0][0];
#pragma unroll
        for (int kk = 0; kk < BK; kk++) {
            float a = as[kk * 64 + lane];                // ds_read_b32
#pragma unroll
            for (int j = 0; j < NOC; j++)
                acc[j] = fmaf(a, bp[kk * OC + j], acc[j]);   // s_load + v_fmac(s,v)
        }
        if (t + 1 < NIT) {
#pragma unroll
            for (int i = 0; i < NR; i++)
                As[(t + 1) & 1][krow + i][lane] = rg[i]; // other buffer: no WAR
            __syncthreads();                             // one barrier / K-step
        }
    }

    // epilogue: bias (+relu), store
#pragma unroll
    for (int j = 0; j < NOC; j++) {
        int oc  = oc0 + j;
        float v = acc[j] + bias[oc];
        if (RELU) v = fmaxf(v, 0.f);
        if (TRANSOUT) out[(size_t)oc * NPIXT + pix] = v;                 // z3t[oc][pix]
        else          out[((size_t)(n * OC + oc)) * HWo + hw] = v;       // NCHW
    }
}

// ---------------------------------------------------------------------------
// VQ: per pixel argmin over 512 codes of |z|^2 - 2 z.c + |c|^2.
// z transposed [64][21632] -> coalesced loads. Codebook reads wave-uniform.
// ---------------------------------------------------------------------------
__global__ __launch_bounds__(256) void vq_kernel(
    const float* __restrict__ zt,           // [64][21632]
    const float* __restrict__ cb,           // [512][64]
    unsigned long long* __restrict__ best)  // [21632], preset to ~0
{
    const int tid  = threadIdx.x;
    const int lane = tid & 63;
    const int wv   = tid >> 6;
    const int pg   = blockIdx.x >> 1;
    const int half = blockIdx.x & 1;
    const int p    = pg * 64 + lane;        // 338*64 == 21632 exactly

    __shared__ float c2s[256];
    {
        int code = half * 256 + tid;
        const float* c = cb + (size_t)code * EMB;
        float s = 0.f;
#pragma unroll
        for (int j = 0; j < EMB; j += 4) {
            float4 v = *(const float4*)(c + j);
            s = fmaf(v.x, v.x, s); s = fmaf(v.y, v.y, s);
            s = fmaf(v.z, v.z, s); s = fmaf(v.w, v.w, s);
        }
        c2s[tid] = s;
    }
    __syncthreads();

    float zr[EMB];
    float zz = 0.f;
#pragma unroll
    for (int j = 0; j < EMB; j++) {
        float v = zt[(size_t)j * NPIXT + p];
        zr[j] = v;
        zz = fmaf(v, v, zz);
    }

    float bestScore = FLT_MAX;
    int   bestIdx   = 0x7fffffff;
    const int base = half * 256 + wv * 64;
    for (int ci = 0; ci < 64; ci++) {
        int code = __builtin_amdgcn_readfirstlane(base + ci);
        const float* c = cb + (size_t)code * EMB;
        float dot = 0.f;
#pragma unroll
        for (int j = 0; j < EMB; j++) dot = fmaf(zr[j], c[j], dot);
        float score = fmaf(-2.f, dot, zz) + c2s[code - half * 256];
        if (score < bestScore) { bestScore = score; bestIdx = code; }
    }

    unsigned u = __float_as_uint(bestScore);
    u = (bestScore < 0.f) ? ~u : (u | 0x80000000u);
    unsigned long long pk = ((unsigned long long)u << 32) | (unsigned)bestIdx;
    atomicMin(&best[p], pk);
}

__global__ __launch_bounds__(256) void onehot_kernel(
    const unsigned long long* __restrict__ best, float* __restrict__ out)
{
    int p = blockIdx.x * 256 + threadIdx.x;
    if (p >= NPIXT) return;
    int code = (int)(unsigned)(best[p] & 0xffffffffu);
    int b  = p / HW3;
    int hw = p - b * HW3;
    out[((size_t)b * NEMB + code) * HW3 + hw] = 1.0f;
}

extern "C" void kernel_launch(void* const* d_in, const int* in_sizes, int n_in,
                              void* d_out, int out_size, void* d_ws, size_t ws_size,
                              hipStream_t stream) {
    const float* x  = (const float*)d_in[0];
    const float* w1 = (const float*)d_in[1];
    const float* b1 = (const float*)d_in[2];
    const float* w2 = (const float*)d_in[3];
    const float* b2 = (const float*)d_in[4];
    const float* w3 = (const float*)d_in[5];
    const float* b3 = (const float*)d_in[6];
    const float* cb = (const float*)d_in[7];
    float* out = (float*)d_out;

    float* z1  = (float*)d_ws;                            // 128*64*48*48   = 75.5 MB
    float* z2  = z1 + (size_t)128 * 64 * 48 * 48;         // 128*128*16*16  = 16.8 MB
    float* z3t = z2 + (size_t)128 * 128 * 16 * 16;        // [64][21632]    =  5.5 MB
    unsigned long long* best = (unsigned long long*)(z3t + (size_t)EMB * NPIXT);
    float* w1t = (float*)(best + NPIXT);                  // [192][64]
    float* w2t = w1t + 192 * 64;                          // [2304][128]
    float* w3t = w2t + 2304 * 128;                        // [2048][64]

    hipMemsetAsync(out, 0, (size_t)out_size * sizeof(float), stream);
    hipMemsetAsync(best, 0xFF, (size_t)NPIXT * sizeof(unsigned long long), stream);

    wtrans_kernel<<<(64 * 192 + 255) / 256, 256, 0, stream>>>(w1, w1t, 64, 192);
    wtrans_kernel<<<(128 * 2304 + 255) / 256, 256, 0, stream>>>(w2, w2t, 128, 2304);
    wtrans_kernel<<<(64 * 2048 + 255) / 256, 256, 0, stream>>>(w3, w3t, 64, 2048);

    // conv1: M = 294912 pixels -> 4608 blocks (18/CU)
    conv_sgemm<3, 64, 8, 8, 192, 192, 48, 48, 4, 2, true, false, 1>
        <<<294912 / 64, 512, 0, stream>>>(x, w1t, b1, z1);
    // conv2: M = 32768 pixels -> 512 blocks, full OC per block
    conv_sgemm<64, 128, 6, 6, 48, 48, 16, 16, 3, 2, true, false, 1>
        <<<32768 / 64, 512, 0, stream>>>(z1, w2t, b2, z2);
    // conv3: OC-split x2 -> 676 blocks, transposed output
    conv_sgemm<128, 64, 4, 4, 16, 16, 13, 13, 1, 0, false, true, 2>
        <<<(NPIXT / 64) * 2, 512, 0, stream>>>(z2, w3t, b3, z3t);

    vq_kernel<<<338 * 2, 256, 0, stream>>>(z3t, cb, best);
    onehot_kernel<<<(NPIXT + 255) / 256, 256, 0, stream>>>(best, out);
}

// Round 5
// 1057.969 us; speedup vs baseline: 1.3773x; 1.3773x over previous
//
#include <hip/hip_runtime.h>
#include <cstdint>
#include <cfloat>

// ---------------------------------------------------------------------------
// SimpleVQVAEEncoder, round 7: R3 base + double-buffered pipeline, with the
// R1/R4 poison removed. Diagnosis: both regressions read the LDS tile via
// `const float* as = &As[t&1][0][0]` — a GENERIC pointer with runtime buffer
// index; InferAddressSpaces fails, every A-read becomes flat_load_dword
// (64-bit VALU addr math + flat path) -> 4.7x VALU-issue blowup.
// This version: NO raw pointers into LDS, NO runtime buffer index. K-loop
// manually two-phased (NIT even: 6/72/64), so As[0]/As[1] are literal
// indices and all LDS access is direct array indexing.
//   phase A: issue loads(t+1) -> FMA on As[0] -> ds_write As[1] -> sync
//   phase B: issue loads(t+2) -> FMA on As[1] -> ds_write As[0] -> sync
// Staging math is R3's verbatim (SALU k-decomp, hoisted pixel decomp).
// ---------------------------------------------------------------------------

constexpr int B_    = 128;
constexpr int HW3   = 169;
constexpr int NPIXT = B_ * HW3;        // 21632
constexpr int NEMB  = 512;
constexpr int EMB   = 64;

// transpose weights [OC][K] -> [K][OC] (tiny prepass)
__global__ __launch_bounds__(256) void wtrans_kernel(
    const float* __restrict__ w, float* __restrict__ wt, int OC, int K)
{
    int idx = blockIdx.x * 256 + threadIdx.x;
    if (idx >= OC * K) return;
    int oc = idx / K, k = idx - oc * K;
    wt[(size_t)k * OC + oc] = w[idx];
}

template<int IC, int OC, int KH, int KW, int IH, int IW, int OH, int OW,
         int STRIDE, int PAD, bool RELU, bool TRANSOUT, int OCSPLIT>
__global__ __launch_bounds__(512) void conv_sgemm(
    const float* __restrict__ in, const float* __restrict__ wt,   // wt: [K][OC]
    const float* __restrict__ bias, float* __restrict__ out)
{
    constexpr int K   = IC * KH * KW;
    constexpr int KHW = KH * KW;
    constexpr int BK  = 32;
    constexpr int NIT = K / BK;            // 6 / 72 / 64 — all even
    static_assert(NIT % 2 == 0, "two-phase loop needs even NIT");
    constexpr int NR  = BK / 8;            // rows staged per wave (4)
    constexpr int NOC = OC / OCSPLIT / 8;  // accs per thread
    constexpr int HWo = OH * OW;

    __shared__ float As[2][BK][64];    // 16 KB; b32 reads: 2-way = free

    const int tid  = threadIdx.x;
    const int lane = tid & 63;
    const int wv   = __builtin_amdgcn_readfirstlane(tid >> 6);  // force uniform
    const int osp  = blockIdx.x % OCSPLIT;
    const int oc0  = osp * (OC / OCSPLIT) + wv * NOC;
    const int pixbase = (blockIdx.x / OCSPLIT) * 64;
    const int krow = wv * NR;              // wave-uniform LDS row base

    // ---- hoisted pixel decomposition (lane-dependent only, once) ----
    const int pix = pixbase + lane;
    const int n   = pix / HWo;
    const int hw  = pix - n * HWo;
    const int oy  = hw / OW;
    const int ox  = hw - oy * OW;
    const int iyb = oy * STRIDE - PAD;
    const int ixb = ox * STRIDE - PAD;
    const float* inb = in + (size_t)n * (IC * IH * IW);

    float acc[NOC];
#pragma unroll
    for (int j = 0; j < NOC; j++) acc[j] = 0.f;

    float rg[NR];
    // R3's staging math, verbatim (k wave-uniform -> SALU decomposition)
    auto stage_load = [&](int k0) {
#pragma unroll
        for (int i = 0; i < NR; i++) {
            int k  = k0 + krow + i;              // uniform
            int ic = k / KHW;                    // uniform -> SALU
            int r  = k - ic * KHW;
            int ky = r / KW;
            int kx = r - ky * KW;
            int iy = iyb + ky;                   // per-lane: 1 add
            int ix = ixb + kx;                   // 1 add
            int off = (ic * IH + iy) * IW + ix;  // mad (ic*IH uniform)
            float v = 0.f;
            if ((unsigned)iy < (unsigned)IH && (unsigned)ix < (unsigned)IW)
                v = inb[off];                    // exec-masked load
            rg[i] = v;
        }
    };

// FMA over one LDS buffer; BUF is a literal -> direct LDS addressing
#define FMA_TILE(BUF, T)                                                   \
    {                                                                      \
        const float* bp = wt + (size_t)((T) * BK) * OC + oc0;              \
        _Pragma("unroll")                                                  \
        for (int kk = 0; kk < BK; kk++) {                                  \
            float a = As[BUF][kk][lane];                                   \
            _Pragma("unroll")                                              \
            for (int j = 0; j < NOC; j++)                                  \
                acc[j] = fmaf(a, bp[kk * OC + j], acc[j]);                 \
        }                                                                  \
    }

    // prologue: tile 0 into buffer 0
    stage_load(0);
#pragma unroll
    for (int i = 0; i < NR; i++) As[0][krow + i][lane] = rg[i];
    __syncthreads();

#pragma unroll 1
    for (int t = 0; t < NIT; t += 2) {
        // phase A: buffer 0 compute, prefetch tile t+1 (always exists)
        stage_load((t + 1) * BK);
        FMA_TILE(0, t);
#pragma unroll
        for (int i = 0; i < NR; i++) As[1][krow + i][lane] = rg[i];
        __syncthreads();

        // phase B: buffer 1 compute, prefetch tile t+2 (unless last pair)
        const bool more = (t + 2 < NIT);
        if (more) stage_load((t + 2) * BK);
        FMA_TILE(1, t + 1);
        if (more) {
#pragma unroll
            for (int i = 0; i < NR; i++) As[0][krow + i][lane] = rg[i];
            __syncthreads();
        }
    }
#undef FMA_TILE

    // epilogue: bias (+relu), store
#pragma unroll
    for (int j = 0; j < NOC; j++) {
        int oc  = oc0 + j;
        float v = acc[j] + bias[oc];
        if (RELU) v = fmaxf(v, 0.f);
        if (TRANSOUT) out[(size_t)oc * NPIXT + pix] = v;                 // z3t[oc][pix]
        else          out[((size_t)(n * OC + oc)) * HWo + hw] = v;       // NCHW
    }
}

// ---------------------------------------------------------------------------
// VQ: per pixel argmin over 512 codes of |z|^2 - 2 z.c + |c|^2.
// z transposed [64][21632] -> coalesced loads. Codebook reads wave-uniform.
// ---------------------------------------------------------------------------
__global__ __launch_bounds__(256) void vq_kernel(
    const float* __restrict__ zt,           // [64][21632]
    const float* __restrict__ cb,           // [512][64]
    unsigned long long* __restrict__ best)  // [21632], preset to ~0
{
    const int tid  = threadIdx.x;
    const int lane = tid & 63;
    const int wv   = tid >> 6;
    const int pg   = blockIdx.x >> 1;
    const int half = blockIdx.x & 1;
    const int p    = pg * 64 + lane;        // 338*64 == 21632 exactly

    __shared__ float c2s[256];
    {
        int code = half * 256 + tid;
        const float* c = cb + (size_t)code * EMB;
        float s = 0.f;
#pragma unroll
        for (int j = 0; j < EMB; j += 4) {
            float4 v = *(const float4*)(c + j);
            s = fmaf(v.x, v.x, s); s = fmaf(v.y, v.y, s);
            s = fmaf(v.z, v.z, s); s = fmaf(v.w, v.w, s);
        }
        c2s[tid] = s;
    }
    __syncthreads();

    float zr[EMB];
    float zz = 0.f;
#pragma unroll
    for (int j = 0; j < EMB; j++) {
        float v = zt[(size_t)j * NPIXT + p];
        zr[j] = v;
        zz = fmaf(v, v, zz);
    }

    float bestScore = FLT_MAX;
    int   bestIdx   = 0x7fffffff;
    const int base = half * 256 + wv * 64;
    for (int ci = 0; ci < 64; ci++) {
        int code = __builtin_amdgcn_readfirstlane(base + ci);
        const float* c = cb + (size_t)code * EMB;
        float dot = 0.f;
#pragma unroll
        for (int j = 0; j < EMB; j++) dot = fmaf(zr[j], c[j], dot);
        float score = fmaf(-2.f, dot, zz) + c2s[code - half * 256];
        if (score < bestScore) { bestScore = score; bestIdx = code; }
    }

    unsigned u = __float_as_uint(bestScore);
    u = (bestScore < 0.f) ? ~u : (u | 0x80000000u);
    unsigned long long pk = ((unsigned long long)u << 32) | (unsigned)bestIdx;
    atomicMin(&best[p], pk);
}

__global__ __launch_bounds__(256) void onehot_kernel(
    const unsigned long long* __restrict__ best, float* __restrict__ out)
{
    int p = blockIdx.x * 256 + threadIdx.x;
    if (p >= NPIXT) return;
    int code = (int)(unsigned)(best[p] & 0xffffffffu);
    int b  = p / HW3;
    int hw = p - b * HW3;
    out[((size_t)b * NEMB + code) * HW3 + hw] = 1.0f;
}

extern "C" void kernel_launch(void* const* d_in, const int* in_sizes, int n_in,
                              void* d_out, int out_size, void* d_ws, size_t ws_size,
                              hipStream_t stream) {
    const float* x  = (const float*)d_in[0];
    const float* w1 = (const float*)d_in[1];
    const float* b1 = (const float*)d_in[2];
    const float* w2 = (const float*)d_in[3];
    const float* b2 = (const float*)d_in[4];
    const float* w3 = (const float*)d_in[5];
    const float* b3 = (const float*)d_in[6];
    const float* cb = (const float*)d_in[7];
    float* out = (float*)d_out;

    float* z1  = (float*)d_ws;                            // 128*64*48*48   = 75.5 MB
    float* z2  = z1 + (size_t)128 * 64 * 48 * 48;         // 128*128*16*16  = 16.8 MB
    float* z3t = z2 + (size_t)128 * 128 * 16 * 16;        // [64][21632]    =  5.5 MB
    unsigned long long* best = (unsigned long long*)(z3t + (size_t)EMB * NPIXT);
    float* w1t = (float*)(best + NPIXT);                  // [192][64]
    float* w2t = w1t + 192 * 64;                          // [2304][128]
    float* w3t = w2t + 2304 * 128;                        // [2048][64]

    hipMemsetAsync(out, 0, (size_t)out_size * sizeof(float), stream);
    hipMemsetAsync(best, 0xFF, (size_t)NPIXT * sizeof(unsigned long long), stream);

    wtrans_kernel<<<(64 * 192 + 255) / 256, 256, 0, stream>>>(w1, w1t, 64, 192);
    wtrans_kernel<<<(128 * 2304 + 255) / 256, 256, 0, stream>>>(w2, w2t, 128, 2304);
    wtrans_kernel<<<(64 * 2048 + 255) / 256, 256, 0, stream>>>(w3, w3t, 64, 2048);

    // conv1: M = 294912 pixels -> 4608 blocks (18/CU)
    conv_sgemm<3, 64, 8, 8, 192, 192, 48, 48, 4, 2, true, false, 1>
        <<<294912 / 64, 512, 0, stream>>>(x, w1t, b1, z1);
    // conv2: M = 32768 pixels -> 512 blocks, full OC per block
    conv_sgemm<64, 128, 6, 6, 48, 48, 16, 16, 3, 2, true, false, 1>
        <<<32768 / 64, 512, 0, stream>>>(z1, w2t, b2, z2);
    // conv3: OC-split x2 -> 676 blocks, transposed output
    conv_sgemm<128, 64, 4, 4, 16, 16, 13, 13, 1, 0, false, true, 2>
        <<<(NPIXT / 64) * 2, 512, 0, stream>>>(z2, w3t, b3, z3t);

    vq_kernel<<<338 * 2, 256, 0, stream>>>(z3t, cb, best);
    onehot_kernel<<<(NPIXT + 255) / 256, 256, 0, stream>>>(best, out);
}

// Round 6
// 662.826 us; speedup vs baseline: 2.1984x; 1.5961x over previous
//
#include <hip/hip_runtime.h>
#include <cstdint>
#include <cfloat>

// ---------------------------------------------------------------------------
// SimpleVQVAEEncoder, round 8: R3 base (689 µs) + ONE change: BK 32 -> 64.
// Pipelining is permanently abandoned (R1/R4/R5: 3 regressions — hipcc
// codegen blows up ~3x VALU issue on any reg-prefetch restructure).
// Keeping R3's exact skeleton: sync -> stage(load->ds_write) -> sync -> FMA,
// direct As[kk][lane] indexing, SALU k-decomposition. BK=64 halves barrier
// count; each barrier pair amortized by 2x the FMA work.
// ---------------------------------------------------------------------------

constexpr int B_    = 128;
constexpr int HW3   = 169;
constexpr int NPIXT = B_ * HW3;        // 21632
constexpr int NEMB  = 512;
constexpr int EMB   = 64;

// transpose weights [OC][K] -> [K][OC] (tiny prepass)
__global__ __launch_bounds__(256) void wtrans_kernel(
    const float* __restrict__ w, float* __restrict__ wt, int OC, int K)
{
    int idx = blockIdx.x * 256 + threadIdx.x;
    if (idx >= OC * K) return;
    int oc = idx / K, k = idx - oc * K;
    wt[(size_t)k * OC + oc] = w[idx];
}

template<int IC, int OC, int KH, int KW, int IH, int IW, int OH, int OW,
         int STRIDE, int PAD, bool RELU, bool TRANSOUT, int OCSPLIT>
__global__ __launch_bounds__(512) void conv_sgemm(
    const float* __restrict__ in, const float* __restrict__ wt,   // wt: [K][OC]
    const float* __restrict__ bias, float* __restrict__ out)
{
    constexpr int K   = IC * KH * KW;
    constexpr int KHW = KH * KW;
    constexpr int BK  = 64;
    static_assert(K % BK == 0, "K must divide by BK");  // 192/2304/2048: ok
    constexpr int NR  = BK / 8;            // rows staged per wave (8)
    constexpr int NOC = OC / OCSPLIT / 8;  // accs per thread
    constexpr int HWo = OH * OW;

    __shared__ float As[BK][64];       // 16 KB; b32 reads: 2-way = free

    const int tid  = threadIdx.x;
    const int lane = tid & 63;
    const int wv   = __builtin_amdgcn_readfirstlane(tid >> 6);  // force uniform
    const int osp  = blockIdx.x % OCSPLIT;
    const int oc0  = osp * (OC / OCSPLIT) + wv * NOC;
    const int pixbase = (blockIdx.x / OCSPLIT) * 64;
    const int krow = wv * NR;              // wave-uniform LDS row base

    // ---- hoisted pixel decomposition (lane-dependent only, once) ----
    const int pix = pixbase + lane;
    const int n   = pix / HWo;
    const int hw  = pix - n * HWo;
    const int oy  = hw / OW;
    const int ox  = hw - oy * OW;
    const int iyb = oy * STRIDE - PAD;
    const int ixb = ox * STRIDE - PAD;
    const float* inb = in + (size_t)n * (IC * IH * IW);

    float acc[NOC];
#pragma unroll
    for (int j = 0; j < NOC; j++) acc[j] = 0.f;

    for (int k0 = 0; k0 < K; k0 += BK) {
        __syncthreads();               // previous iter's reads done
#pragma unroll
        for (int i = 0; i < NR; i++) {
            int kk = krow + i;                   // wave-uniform row
            int k  = k0 + kk;                    // uniform
            int ic = k / KHW;                    // uniform -> SALU
            int r  = k - ic * KHW;
            int ky = r / KW;
            int kx = r - ky * KW;
            int iy = iyb + ky;                   // per-lane: 1 add
            int ix = ixb + kx;                   // 1 add
            int off = (ic * IH + iy) * IW + ix;  // mad (ic*IH uniform)
            float v = 0.f;
            if ((unsigned)iy < (unsigned)IH && (unsigned)ix < (unsigned)IW)
                v = inb[off];                    // exec-masked load
            As[kk][lane] = v;
        }
        __syncthreads();

        const float* bp = wt + (size_t)k0 * OC + oc0;    // wave-uniform address
#pragma unroll
        for (int kk = 0; kk < BK; kk++) {
            float a = As[kk][lane];
#pragma unroll
            for (int j = 0; j < NOC; j++)
                acc[j] = fmaf(a, bp[kk * OC + j], acc[j]);   // s_load + v_fmac(s,v)
        }
    }

    // epilogue: bias (+relu), store
#pragma unroll
    for (int j = 0; j < NOC; j++) {
        int oc  = oc0 + j;
        float v = acc[j] + bias[oc];
        if (RELU) v = fmaxf(v, 0.f);
        if (TRANSOUT) out[(size_t)oc * NPIXT + pix] = v;                 // z3t[oc][pix]
        else          out[((size_t)(n * OC + oc)) * HWo + hw] = v;       // NCHW
    }
}

// ---------------------------------------------------------------------------
// VQ: per pixel argmin over 512 codes of |z|^2 - 2 z.c + |c|^2.
// z transposed [64][21632] -> coalesced loads. Codebook reads wave-uniform.
// ---------------------------------------------------------------------------
__global__ __launch_bounds__(256) void vq_kernel(
    const float* __restrict__ zt,           // [64][21632]
    const float* __restrict__ cb,           // [512][64]
    unsigned long long* __restrict__ best)  // [21632], preset to ~0
{
    const int tid  = threadIdx.x;
    const int lane = tid & 63;
    const int wv   = tid >> 6;
    const int pg   = blockIdx.x >> 1;
    const int half = blockIdx.x & 1;
    const int p    = pg * 64 + lane;        // 338*64 == 21632 exactly

    __shared__ float c2s[256];
    {
        int code = half * 256 + tid;
        const float* c = cb + (size_t)code * EMB;
        float s = 0.f;
#pragma unroll
        for (int j = 0; j < EMB; j += 4) {
            float4 v = *(const float4*)(c + j);
            s = fmaf(v.x, v.x, s); s = fmaf(v.y, v.y, s);
            s = fmaf(v.z, v.z, s); s = fmaf(v.w, v.w, s);
        }
        c2s[tid] = s;
    }
    __syncthreads();

    float zr[EMB];
    float zz = 0.f;
#pragma unroll
    for (int j = 0; j < EMB; j++) {
        float v = zt[(size_t)j * NPIXT + p];
        zr[j] = v;
        zz = fmaf(v, v, zz);
    }

    float bestScore = FLT_MAX;
    int   bestIdx   = 0x7fffffff;
    const int base = half * 256 + wv * 64;
    for (int ci = 0; ci < 64; ci++) {
        int code = __builtin_amdgcn_readfirstlane(base + ci);
        const float* c = cb + (size_t)code * EMB;
        float dot = 0.f;
#pragma unroll
        for (int j = 0; j < EMB; j++) dot = fmaf(zr[j], c[j], dot);
        float score = fmaf(-2.f, dot, zz) + c2s[code - half * 256];
        if (score < bestScore) { bestScore = score; bestIdx = code; }
    }

    unsigned u = __float_as_uint(bestScore);
    u = (bestScore < 0.f) ? ~u : (u | 0x80000000u);
    unsigned long long pk = ((unsigned long long)u << 32) | (unsigned)bestIdx;
    atomicMin(&best[p], pk);
}

__global__ __launch_bounds__(256) void onehot_kernel(
    const unsigned long long* __restrict__ best, float* __restrict__ out)
{
    int p = blockIdx.x * 256 + threadIdx.x;
    if (p >= NPIXT) return;
    int code = (int)(unsigned)(best[p] & 0xffffffffu);
    int b  = p / HW3;
    int hw = p - b * HW3;
    out[((size_t)b * NEMB + code) * HW3 + hw] = 1.0f;
}

extern "C" void kernel_launch(void* const* d_in, const int* in_sizes, int n_in,
                              void* d_out, int out_size, void* d_ws, size_t ws_size,
                              hipStream_t stream) {
    const float* x  = (const float*)d_in[0];
    const float* w1 = (const float*)d_in[1];
    const float* b1 = (const float*)d_in[2];
    const float* w2 = (const float*)d_in[3];
    const float* b2 = (const float*)d_in[4];
    const float* w3 = (const float*)d_in[5];
    const float* b3 = (const float*)d_in[6];
    const float* cb = (const float*)d_in[7];
    float* out = (float*)d_out;

    float* z1  = (float*)d_ws;                            // 128*64*48*48   = 75.5 MB
    float* z2  = z1 + (size_t)128 * 64 * 48 * 48;         // 128*128*16*16  = 16.8 MB
    float* z3t = z2 + (size_t)128 * 128 * 16 * 16;        // [64][21632]    =  5.5 MB
    unsigned long long* best = (unsigned long long*)(z3t + (size_t)EMB * NPIXT);
    float* w1t = (float*)(best + NPIXT);                  // [192][64]
    float* w2t = w1t + 192 * 64;                          // [2304][128]
    float* w3t = w2t + 2304 * 128;                        // [2048][64]

    hipMemsetAsync(out, 0, (size_t)out_size * sizeof(float), stream);
    hipMemsetAsync(best, 0xFF, (size_t)NPIXT * sizeof(unsigned long long), stream);

    wtrans_kernel<<<(64 * 192 + 255) / 256, 256, 0, stream>>>(w1, w1t, 64, 192);
    wtrans_kernel<<<(128 * 2304 + 255) / 256, 256, 0, stream>>>(w2, w2t, 128, 2304);
    wtrans_kernel<<<(64 * 2048 + 255) / 256, 256, 0, stream>>>(w3, w3t, 64, 2048);

    // conv1: M = 294912 pixels -> 4608 blocks (18/CU)
    conv_sgemm<3, 64, 8, 8, 192, 192, 48, 48, 4, 2, true, false, 1>
        <<<294912 / 64, 512, 0, stream>>>(x, w1t, b1, z1);
    // conv2: M = 32768 pixels -> 512 blocks, full OC per block
    conv_sgemm<64, 128, 6, 6, 48, 48, 16, 16, 3, 2, true, false, 1>
        <<<32768 / 64, 512, 0, stream>>>(z1, w2t, b2, z2);
    // conv3: OC-split x2 -> 676 blocks, transposed output
    conv_sgemm<128, 64, 4, 4, 16, 16, 13, 13, 1, 0, false, true, 2>
        <<<(NPIXT / 64) * 2, 512, 0, stream>>>(z2, w3t, b3, z3t);

    vq_kernel<<<338 * 2, 256, 0, stream>>>(z3t, cb, best);
    onehot_kernel<<<(NPIXT + 255) / 256, 256, 0, stream>>>(best, out);
}